// Round 2
// baseline (259.214 us; speedup 1.0000x reference)
//
#include <hip/hip_runtime.h>

#define N_CELLTYPE 50
#define M_PER_CT   2000
#define N_FEATURE  20000
#define N_CELL     512
#define R_TOTAL    (N_CELLTYPE * M_PER_CT)   // 100000 rows of z
#define NTHREADS   1024
#define NBLOCKS    (N_CELL / 2)              // 256 blocks, one column PAIR each

typedef float vfloat4 __attribute__((ext_vector_type(4)));

// Column-pair-owner kernel.
//   Each block owns output columns c0, c0+1 ENTIRELY:
//     Phase A: stage x[:, c0:c0+2] into LDS (20000 x float2 = 156.25 KiB).
//     Phase B: stream idx (coalesced, identical across blocks -> L2 broadcast),
//              gather float2 from LDS (one b64 serves BOTH columns),
//              write two 400KB PURELY SEQUENTIAL nt-store streams.
//   Rationale: rounds 0/1 showed burst length (128B vs 1KB) is irrelevant —
//   scattered-chunk writes run at random-access DRAM efficiency (~2 TB/s).
//   512 long sequential streams is the fill-like pattern that hits 6.5 TB/s.
// LDS 156.5 KiB -> 1 block/CU, 16 waves; grid 256 = fully resident, 1/CU.
__global__ __launch_bounds__(NTHREADS) void ct_colpair(
    const float* __restrict__ x, const float* __restrict__ w,
    const int* __restrict__ idx, float* __restrict__ out) {
  __shared__ float xl[N_FEATURE * 2];   // xl[2f], xl[2f+1] = x[f][c0], x[f][c0+1]
  __shared__ float sw[N_CELLTYPE];

  // XCD-aware mapping: blocks dispatch round-robin over 8 XCDs (b%8), so give
  // XCD k the 64 consecutive columns [64k, 64k+64) -> its L2 only needs that
  // 2x2.56MB slice of x-lines (vs 41MB without the remap).
  const int b  = blockIdx.x;
  const int c0 = 2 * ((b & 7) * 32 + (b >> 3));   // bijective onto even cols
  const int t  = threadIdx.x;

  if (t < N_CELLTYPE) sw[t] = w[t];

  // Phase A: 20 iters x float2; wave = 64 consecutive features -> 64 distinct
  // 128B lines per instr (compulsory; shared with the XCD's sibling blocks).
#pragma unroll
  for (int i = 0; i < 20; ++i) {
    const int f = i * NTHREADS + t;
    if (f < N_FEATURE) {
      const float2 v =
          *reinterpret_cast<const float2*>(x + (long)f * N_CELL + c0);
      *reinterpret_cast<float2*>(&xl[f * 2]) = v;   // b64, conflict-free
    }
  }
  __syncthreads();

  // Phase B: 25 iters; per iter each thread handles 4 consecutive rows.
  // idx int4 load = 1KB/wave coalesced; 4 random LDS b64 gathers; two float4
  // nt stores advancing two sequential column streams 16KB/iter.
  float* o0 = out + (long)c0 * R_TOTAL;
  float* o1 = o0 + R_TOTAL;
#pragma unroll 2
  for (int rb = 0; rb < R_TOTAL; rb += NTHREADS * 4) {
    const int r = rb + t * 4;
    if (r < R_TOTAL) {                 // r%4==0 and 100000%4==0 -> r+3 in range
      const int4 f4 = *reinterpret_cast<const int4*>(idx + r);
      const float s = sw[r / M_PER_CT];   // 2000%4==0 -> same ct for r..r+3
      const float2 g0 = *reinterpret_cast<const float2*>(&xl[f4.x * 2]);
      const float2 g1 = *reinterpret_cast<const float2*>(&xl[f4.y * 2]);
      const float2 g2 = *reinterpret_cast<const float2*>(&xl[f4.z * 2]);
      const float2 g3 = *reinterpret_cast<const float2*>(&xl[f4.w * 2]);
      vfloat4 v0, v1;
      v0.x = g0.x * s; v0.y = g1.x * s; v0.z = g2.x * s; v0.w = g3.x * s;
      v1.x = g0.y * s; v1.y = g1.y * s; v1.z = g2.y * s; v1.w = g3.y * s;
      __builtin_nontemporal_store(v0, reinterpret_cast<vfloat4*>(o0 + r));
      __builtin_nontemporal_store(v1, reinterpret_cast<vfloat4*>(o1 + r));
    }
  }
}

extern "C" void kernel_launch(void* const* d_in, const int* in_sizes, int n_in,
                              void* d_out, int out_size, void* d_ws, size_t ws_size,
                              hipStream_t stream) {
  const float* x   = (const float*)d_in[0];
  const float* w   = (const float*)d_in[1];
  const int*   idx = (const int*)d_in[2];
  float*       out = (float*)d_out;

  ct_colpair<<<dim3(NBLOCKS), dim3(NTHREADS), 0, stream>>>(x, w, idx, out);
}

// Round 3
// 242.665 us; speedup vs baseline: 1.0682x; 1.0682x over previous
//
#include <hip/hip_runtime.h>

#define N_CELLTYPE 50
#define M_PER_CT   2000
#define N_FEATURE  20000
#define N_CELL     512
#define R_TOTAL    (N_CELLTYPE * M_PER_CT)   // 100000 rows of z
#define TR         256                       // rows per tile (tail tile: 160 rows)
#define TC         32                        // cols per tile (512/32 = 16 exact)
#define NTHREADS   512
#define NRT        ((R_TOTAL + TR - 1) / TR) // 391 row tiles (390*256 + 160)

typedef float vfloat4 __attribute__((ext_vector_type(4)));

// Round-3 A/B: identical to the round-1 kernel EXCEPT plain stores instead of
// __builtin_nontemporal_store. Evidence: three different write patterns
// (128B scattered / 1KB scattered / fully sequential streams) all ran at
// ~1.6-1.7 TB/s effective write BW with nt-stores, while the harness fill
// does 6.5 TB/s with plain stores on the same buffer. Theory: the nt path
// itself caps at ~1.7 TB/s; write-combining through L2 is the fill's secret.
// (x is 41MB vs 256MB L3, so the original "avoid evicting x" nt rationale
// costs more than it saves.)
__global__ __launch_bounds__(NTHREADS) void ct_scale_transpose(
    const float* __restrict__ x, const float* __restrict__ w,
    const int* __restrict__ idx, float* __restrict__ out) {
  __shared__ float tile[TC][TR];   // 32KB; + srow/sw = 34KB -> 4 blocks/CU
  __shared__ int   srow[TR];
  __shared__ float sw[TR];

  const int r0 = blockIdx.x * TR;
  const int c0 = blockIdx.y * TC;
  const int t  = threadIdx.x;

  if (t < TR) {
    const int r = r0 + t;
    if (r < R_TOTAL) {
      srow[t] = idx[r];
      sw[t]   = w[r / M_PER_CT];
    } else {              // tail tile: harmless dummy row, output is guarded
      srow[t] = 0;
      sw[t]   = 0.0f;
    }
  }
  __syncthreads();

  // Load phase: 256 rows x 8 float4 = 2048 float4, 4/thread.
  // Per wave instr: 8 rows x 128B aligned contiguous segments (full lines).
#pragma unroll
  for (int i = 0; i < 4; ++i) {
    const int linear = i * NTHREADS + t;
    const int row = linear >> 3;    // 0..255
    const int q   = linear & 7;     // float4 index within the 32-col slice
    const float4 v = *reinterpret_cast<const float4*>(
        x + (long)srow[row] * N_CELL + c0 + q * 4);
    const float s = sw[row];
    const float e[4] = {v.x * s, v.y * s, v.z * s, v.w * s};
#pragma unroll
    for (int j = 0; j < 4; ++j) {
      const int c    = q * 4 + j;
      const int rswz = row ^ (((c >> 1) & 7) << 2);  // XOR-swizzle bits 2..4
      tile[c][rswz] = e[j];
    }
  }
  __syncthreads();

  // Store phase: 32 cols x 64 float4-chunks = 2048 float4, 4/thread.
  // c = linear>>6 is wave-uniform; lane picks the 4-row chunk ->
  // each wave-store is a single 1KB contiguous aligned burst in one column.
#pragma unroll
  for (int i = 0; i < 4; ++i) {
    const int linear = i * NTHREADS + t;
    const int c    = linear >> 6;               // 0..31, fixed per wave
    const int lane = linear & 63;               // 4-row chunk index
    const int m    = lane ^ ((c >> 1) & 7);     // de-swizzled float4 slot
    const int r    = r0 + lane * 4;
    if (r < R_TOTAL) {                          // tail tile: lanes 0..39 active
      const vfloat4 v = *reinterpret_cast<const vfloat4*>(&tile[c][m * 4]);
      *reinterpret_cast<vfloat4*>(out + (long)(c0 + c) * R_TOTAL + r) = v;
    }
  }
}

extern "C" void kernel_launch(void* const* d_in, const int* in_sizes, int n_in,
                              void* d_out, int out_size, void* d_ws, size_t ws_size,
                              hipStream_t stream) {
  const float* x   = (const float*)d_in[0];
  const float* w   = (const float*)d_in[1];
  const int*   idx = (const int*)d_in[2];
  float*       out = (float*)d_out;

  dim3 grid(NRT, N_CELL / TC);   // 391 x 16 = 6256 blocks
  ct_scale_transpose<<<grid, NTHREADS, 0, stream>>>(x, w, idx, out);
}